// Round 1
// baseline (1622.631 us; speedup 1.0000x reference)
//
#include <hip/hip_runtime.h>

#define TT   4
#define BBB  4
#define NNN  4096
#define CCC  512
#define HHH  8
#define DDD  64
#define PTOT (BBB*NNN)      /* 16384 tokens */
#define MROWS (TT*PTOT)     /* 65536 rows */

#define TILE_P 32
#define MT     128          /* TT*TILE_P rows per k1 tile */
#define BK     32

// ---------------------------------------------------------------------------
// Kernel 1: fused QKV projection (fp32 GEMM) + spiking attention per head.
// Grid: (PTOT/TILE_P)*HHH = 4096 blocks, 256 threads.
// Each block: 32 tokens x 1 head x all 4 timesteps -> 128x64 tile, K=512.
// ---------------------------------------------------------------------------
__global__ __launch_bounds__(256, 2)
void k1_qkv_attn(const float* __restrict__ x,
                 const float* __restrict__ Wq, const float* __restrict__ bq,
                 const float* __restrict__ Wk, const float* __restrict__ bk,
                 const float* __restrict__ Wv, const float* __restrict__ bv,
                 float* __restrict__ outp)
{
    // LDS: staging region (sx 32x132 + sw 3x32x68 = 43008 B) unioned with
    // attention region (k,v each 128x68 = 69632 B total). Max = 69632 B.
    __shared__ __align__(16) char smem[69632];
    float (*sx)[MT+4]          = reinterpret_cast<float(*)[MT+4]>(smem);
    float (*sw)[BK][DDD+4]     = reinterpret_cast<float(*)[BK][DDD+4]>(smem + sizeof(float)*BK*(MT+4));
    float (*kT)[DDD+4]         = reinterpret_cast<float(*)[DDD+4]>(smem);
    float (*vT)[DDD+4]         = reinterpret_cast<float(*)[DDD+4]>(smem + sizeof(float)*MT*(DDD+4));

    const int tid = threadIdx.x;
    const int bid = blockIdx.x;
    const int h   = bid & 7;
    const int p0  = (bid >> 3) * TILE_P;

    const int rm   = tid >> 3;          // 0..31 : row group (4 rows each)
    const int cn   = tid & 7;           // 0..7  : col group (8 cols each)
    const int col0 = h*DDD + cn*8;      // global output column base

    // accumulators (init with bias; biases are zero here but kept general)
    float accq[4][8], acck[4][8], accv[4][8];
    #pragma unroll
    for (int d = 0; d < 8; ++d) {
        const float vq = bq[col0+d], vk = bk[col0+d], vv = bv[col0+d];
        #pragma unroll
        for (int i = 0; i < 4; ++i) { accq[i][d]=vq; acck[i][d]=vk; accv[i][d]=vv; }
    }

    // staging address precompute: x tile = 128 rows x 32 k, 1024 float4 slots
    const float* xsrc[4]; int xsk[4], xsr[4];
    #pragma unroll
    for (int jj = 0; jj < 4; ++jj) {
        const int flat = tid + 256*jj;       // 0..1023
        const int r    = flat >> 3;          // 0..127
        const int c4   = flat & 7;           // 0..7
        const int ttr  = r >> 5, j = r & 31;
        xsrc[jj] = x + (size_t)(ttr*PTOT + p0 + j)*CCC + c4*4;
        xsk[jj]  = c4*4; xsr[jj] = r;
    }
    // W tiles: 3 x (64 rows x 32 k) = 1536 float4 slots
    const float* wsrc[6]; int wsw[6], wsk[6], wsr[6];
    #pragma unroll
    for (int jj = 0; jj < 6; ++jj) {
        const int flat = tid + 256*jj;       // 0..1535
        const int w    = flat >> 9;          // 0..2
        const int rem  = flat & 511;
        const int ro   = rem >> 3;           // 0..63
        const int c4   = rem & 7;
        const float* Wp = (w == 0) ? Wq : ((w == 1) ? Wk : Wv);
        wsrc[jj] = Wp + (size_t)(h*DDD + ro)*CCC + c4*4;
        wsw[jj] = w; wsk[jj] = c4*4; wsr[jj] = ro;
    }

    // ---- main K loop ----
    for (int kt = 0; kt < CCC/BK; ++kt) {
        const int k0 = kt*BK;
        __syncthreads();
        #pragma unroll
        for (int jj = 0; jj < 4; ++jj) {
            const float4 t4 = *(const float4*)(xsrc[jj] + k0);
            sx[xsk[jj]+0][xsr[jj]] = t4.x;
            sx[xsk[jj]+1][xsr[jj]] = t4.y;
            sx[xsk[jj]+2][xsr[jj]] = t4.z;
            sx[xsk[jj]+3][xsr[jj]] = t4.w;
        }
        #pragma unroll
        for (int jj = 0; jj < 6; ++jj) {
            const float4 t4 = *(const float4*)(wsrc[jj] + k0);
            sw[wsw[jj]][wsk[jj]+0][wsr[jj]] = t4.x;
            sw[wsw[jj]][wsk[jj]+1][wsr[jj]] = t4.y;
            sw[wsw[jj]][wsk[jj]+2][wsr[jj]] = t4.z;
            sw[wsw[jj]][wsk[jj]+3][wsr[jj]] = t4.w;
        }
        __syncthreads();

        #pragma unroll 4
        for (int kk = 0; kk < BK; ++kk) {
            const float4 av  = *(const float4*)&sx[kk][rm*4];
            const float4 q0_ = *(const float4*)&sw[0][kk][cn*8];
            const float4 q1_ = *(const float4*)&sw[0][kk][cn*8+4];
            const float4 k0_ = *(const float4*)&sw[1][kk][cn*8];
            const float4 k1_ = *(const float4*)&sw[1][kk][cn*8+4];
            const float4 v0_ = *(const float4*)&sw[2][kk][cn*8];
            const float4 v1_ = *(const float4*)&sw[2][kk][cn*8+4];
            const float ar[4] = {av.x, av.y, av.z, av.w};
            const float qb[8] = {q0_.x,q0_.y,q0_.z,q0_.w,q1_.x,q1_.y,q1_.z,q1_.w};
            const float kb[8] = {k0_.x,k0_.y,k0_.z,k0_.w,k1_.x,k1_.y,k1_.z,k1_.w};
            const float vb[8] = {v0_.x,v0_.y,v0_.z,v0_.w,v1_.x,v1_.y,v1_.z,v1_.w};
            #pragma unroll
            for (int i = 0; i < 4; ++i) {
                #pragma unroll
                for (int d = 0; d < 8; ++d) {
                    accq[i][d] += ar[i]*qb[d];
                    acck[i][d] += ar[i]*kb[d];
                    accv[i][d] += ar[i]*vb[d];
                }
            }
        }
    }

    // ---- attention ----
    __syncthreads();   // all staging reads done; safe to overwrite LDS
    #pragma unroll
    for (int i = 0; i < 4; ++i) {
        const int r = rm*4 + i;
        *(float4*)&kT[r][cn*8]   = make_float4(acck[i][0],acck[i][1],acck[i][2],acck[i][3]);
        *(float4*)&kT[r][cn*8+4] = make_float4(acck[i][4],acck[i][5],acck[i][6],acck[i][7]);
        *(float4*)&vT[r][cn*8]   = make_float4(accv[i][0],accv[i][1],accv[i][2],accv[i][3]);
        *(float4*)&vT[r][cn*8+4] = make_float4(accv[i][4],accv[i][5],accv[i][6],accv[i][7]);
    }
    __syncthreads();

    // scores: s[t=thread's tt][ss] for this thread's 4 tokens.
    // spike <=> (dot/8)/2 >= 1  <=> dot >= 16  (exact: /8,/2 are exact in fp32)
    const int jbase = (rm & 7) * 4;
    float sc[4][4];
    #pragma unroll
    for (int i = 0; i < 4; ++i) {
        const int j = jbase + i;
        #pragma unroll
        for (int ss = 0; ss < 4; ++ss) {
            const float* kr = &kT[ss*TILE_P + j][cn*8];
            float p = 0.f;
            #pragma unroll
            for (int d = 0; d < 8; ++d) p += accq[i][d]*kr[d];
            sc[i][ss] = p;
        }
    }
    #pragma unroll
    for (int i = 0; i < 4; ++i) {
        #pragma unroll
        for (int ss = 0; ss < 4; ++ss) {
            float p = sc[i][ss];
            p += __shfl_xor(p, 1);
            p += __shfl_xor(p, 2);
            p += __shfl_xor(p, 4);
            sc[i][ss] = p;     // full 64-wide dot, shared by all 8 cn lanes
        }
    }

    float acco[4][8];
    #pragma unroll
    for (int i = 0; i < 4; ++i)
        #pragma unroll
        for (int d = 0; d < 8; ++d) acco[i][d] = 0.f;

    #pragma unroll
    for (int i = 0; i < 4; ++i) {
        const int j = jbase + i;
        #pragma unroll
        for (int ss = 0; ss < 4; ++ss) {
            if (sc[i][ss] >= 16.0f) {
                const float* vr = &vT[ss*TILE_P + j][cn*8];
                #pragma unroll
                for (int d = 0; d < 8; ++d) acco[i][d] += vr[d];
            }
        }
    }

    // write pre-Wo activation
    #pragma unroll
    for (int i = 0; i < 4; ++i) {
        const int r  = rm*4 + i;
        const int tt = r >> 5, j = r & 31;
        float* op = outp + (size_t)(tt*PTOT + p0 + j)*CCC + col0;
        *(float4*)op     = make_float4(acco[i][0],acco[i][1],acco[i][2],acco[i][3]);
        *(float4*)(op+4) = make_float4(acco[i][4],acco[i][5],acco[i][6],acco[i][7]);
    }
}

// ---------------------------------------------------------------------------
// Kernel 2: out = A @ Wo^T + bo   (65536 x 512, K=512), fp32, 128x128 tiles.
// Grid: 512*4 = 2048 blocks, 256 threads.
// ---------------------------------------------------------------------------
__global__ __launch_bounds__(256, 2)
void k2_gemm(const float* __restrict__ A, const float* __restrict__ W,
             const float* __restrict__ b, float* __restrict__ out)
{
    __shared__ __align__(16) float sa[BK][128+4];
    __shared__ __align__(16) float sb[BK][128+4];

    const int tid = threadIdx.x;
    const int bn  = (blockIdx.x & 3) * 128;
    const size_t bm = (size_t)(blockIdx.x >> 2) * 128;
    const int tx = tid & 15, ty = tid >> 4;   // 16x16 threads, 8x8 micro-tile

    float acc[8][8];
    #pragma unroll
    for (int ci = 0; ci < 8; ++ci) {
        const float bb = b[bn + tx*8 + ci];
        #pragma unroll
        for (int ri = 0; ri < 8; ++ri) acc[ri][ci] = bb;
    }

    const float* asrc[4]; const float* bsrc[4]; int sr[4], sk4[4];
    #pragma unroll
    for (int jj = 0; jj < 4; ++jj) {
        const int flat = tid + 256*jj;   // 0..1023
        const int r = flat >> 3, c4 = flat & 7;
        asrc[jj] = A + (bm + r)*CCC + c4*4;
        bsrc[jj] = W + (size_t)(bn + r)*CCC + c4*4;
        sr[jj] = r; sk4[jj] = c4*4;
    }

    for (int kt = 0; kt < CCC/BK; ++kt) {
        const int k0 = kt*BK;
        __syncthreads();
        #pragma unroll
        for (int jj = 0; jj < 4; ++jj) {
            const float4 ta = *(const float4*)(asrc[jj] + k0);
            sa[sk4[jj]+0][sr[jj]] = ta.x;
            sa[sk4[jj]+1][sr[jj]] = ta.y;
            sa[sk4[jj]+2][sr[jj]] = ta.z;
            sa[sk4[jj]+3][sr[jj]] = ta.w;
            const float4 tb = *(const float4*)(bsrc[jj] + k0);
            sb[sk4[jj]+0][sr[jj]] = tb.x;
            sb[sk4[jj]+1][sr[jj]] = tb.y;
            sb[sk4[jj]+2][sr[jj]] = tb.z;
            sb[sk4[jj]+3][sr[jj]] = tb.w;
        }
        __syncthreads();

        #pragma unroll 4
        for (int kk = 0; kk < BK; ++kk) {
            const float4 a0 = *(const float4*)&sa[kk][ty*8];
            const float4 a1 = *(const float4*)&sa[kk][ty*8+4];
            const float4 b0 = *(const float4*)&sb[kk][tx*8];
            const float4 b1 = *(const float4*)&sb[kk][tx*8+4];
            const float arr[8] = {a0.x,a0.y,a0.z,a0.w,a1.x,a1.y,a1.z,a1.w};
            const float brr[8] = {b0.x,b0.y,b0.z,b0.w,b1.x,b1.y,b1.z,b1.w};
            #pragma unroll
            for (int ri = 0; ri < 8; ++ri)
                #pragma unroll
                for (int ci = 0; ci < 8; ++ci)
                    acc[ri][ci] += arr[ri]*brr[ci];
        }
    }

    #pragma unroll
    for (int ri = 0; ri < 8; ++ri) {
        const size_t row = bm + ty*8 + ri;
        float* op = out + row*CCC + bn + tx*8;
        *(float4*)op     = make_float4(acc[ri][0],acc[ri][1],acc[ri][2],acc[ri][3]);
        *(float4*)(op+4) = make_float4(acc[ri][4],acc[ri][5],acc[ri][6],acc[ri][7]);
    }
}

// ---------------------------------------------------------------------------
extern "C" void kernel_launch(void* const* d_in, const int* in_sizes, int n_in,
                              void* d_out, int out_size, void* d_ws, size_t ws_size,
                              hipStream_t stream)
{
    const float* x  = (const float*)d_in[0];
    const float* Wq = (const float*)d_in[1];
    const float* bq = (const float*)d_in[2];
    const float* Wk = (const float*)d_in[3];
    const float* bk = (const float*)d_in[4];
    const float* Wv = (const float*)d_in[5];
    const float* bv = (const float*)d_in[6];
    const float* Wo = (const float*)d_in[7];
    const float* bo = (const float*)d_in[8];

    float* outp = (float*)d_ws;        // pre-Wo activation: 65536*512*4 = 134 MB
    float* out  = (float*)d_out;

    hipLaunchKernelGGL(k1_qkv_attn, dim3((PTOT/TILE_P)*HHH), dim3(256), 0, stream,
                       x, Wq, bq, Wk, bk, Wv, bv, outp);
    hipLaunchKernelGGL(k2_gemm, dim3((MROWS/128)*(CCC/128)), dim3(256), 0, stream,
                       outp, Wo, bo, out);
}

// Round 2
// 909.090 us; speedup vs baseline: 1.7849x; 1.7849x over previous
//
#include <hip/hip_runtime.h>

#define TT    4
#define PTOT  16384
#define MROWS 65536
#define CCC   512
#define HHH   8
#define BK    32
#define NSTEP (CCC/BK)

typedef __attribute__((ext_vector_type(4))) float f32x4;
typedef __attribute__((ext_vector_type(8))) short s16x8;

#define MFMA_BF16(a,b,c) __builtin_amdgcn_mfma_f32_16x16x32_bf16(a,b,c,0,0,0)

__device__ __forceinline__ unsigned short f2bf(float f) {
    unsigned int u = __float_as_uint(f);
    u += 0x7fffu + ((u >> 16) & 1u);     // RNE to bf16
    return (unsigned short)(u >> 16);
}
__device__ __forceinline__ float bf2f(unsigned short s) {
    return __uint_as_float(((unsigned int)s) << 16);
}

// split fp32 exactly into 3 bf16 terms (hi/mid/lo)
__device__ __forceinline__ void split3(float v, unsigned short& u0,
                                       unsigned short& u1, unsigned short& u2) {
    u0 = f2bf(v);
    float r1 = v - bf2f(u0);
    u1 = f2bf(r1);
    u2 = f2bf(r1 - bf2f(u1));
}

// ---------------------------------------------------------------------------
// k1: fused QKV projection (bf16x3 MFMA) + spiking attention.
// Block: 256 threads (4 waves), 32 tokens x 4 t = 128 rows, 1 head (192 cols:
// q|k|v 64 each), K=512. Wave wv owns col-frag [16wv,16wv+16) of each of q,k,v.
// LDS: staging sx[3][128][40] bf16 (30720B) + sw[512][40] bf16 (40960B) = 71680B,
// overlaid by attention arrays qa/ka/va [64][68] f32 (52224B).
// ---------------------------------------------------------------------------
__global__ __launch_bounds__(256, 2)
void k1_mfma(const float* __restrict__ x,
             const float* __restrict__ Wq, const float* __restrict__ bq,
             const float* __restrict__ Wk, const float* __restrict__ bk,
             const float* __restrict__ Wv, const float* __restrict__ bv,
             float* __restrict__ outp)
{
    __shared__ __align__(16) char smem[71680];
    unsigned short* sx = (unsigned short*)smem;            // [3][128][40]
    unsigned short* sw = (unsigned short*)(smem + 30720);  // [512][40]

    const int tid  = threadIdx.x;
    const int lane = tid & 63;
    const int wv   = tid >> 6;      // wave 0..3 -> col-frag
    const int l15  = lane & 15;
    const int l4   = lane >> 4;     // 0..3
    const int bid  = blockIdx.x;
    const int h    = bid & 7;       // head (== XCD via %8 round-robin: W L2-local)
    const int p0   = (bid >> 3) * 32;

    // ---- staging addresses ----
    // x: slots tid, tid+256: row r = slot>>2 (0..127, r = t*32+j), k8 = slot&3
    const int xr0 = tid >> 2;
    const int xr1 = xr0 + 64;
    const int xk  = (tid & 3) * 8;
    const float* xg0 = x + ((size_t)(xr0 >> 5) * PTOT + p0 + (xr0 & 31)) * CCC + xk;
    const float* xg1 = x + ((size_t)(xr1 >> 5) * PTOT + p0 + (xr1 & 31)) * CCC + xk;
    // W: slot i -> mat i (q,k,v), n = tid>>2 (0..63), same k8
    const int wn = tid >> 2;
    const float* wg0 = Wq + ((size_t)(h*64 + wn)) * CCC + xk;
    const float* wg1 = Wk + ((size_t)(h*64 + wn)) * CCC + xk;
    const float* wg2 = Wv + ((size_t)(h*64 + wn)) * CCC + xk;

    // ---- accumulators (bias-init; C/D frag: col=lane&15, row=(lane>>4)*4+reg) ----
    const float bqv = bq[h*64 + wv*16 + l15];
    const float bkv = bk[h*64 + wv*16 + l15];
    const float bvv = bv[h*64 + wv*16 + l15];
    f32x4 acc[8][3];
    #pragma unroll
    for (int fb = 0; fb < 8; ++fb) {
        acc[fb][0] = f32x4{bqv, bqv, bqv, bqv};
        acc[fb][1] = f32x4{bkv, bkv, bkv, bkv};
        acc[fb][2] = f32x4{bvv, bvv, bvv, bvv};
    }

    // ---- prefetch chunk 0 into registers ----
    float4 pxa0, pxb0, pxa1, pxb1, pwa0, pwb0, pwa1, pwb1, pwa2, pwb2;
    pxa0 = *(const float4*)(xg0);     pxb0 = *(const float4*)(xg0 + 4);
    pxa1 = *(const float4*)(xg1);     pxb1 = *(const float4*)(xg1 + 4);
    pwa0 = *(const float4*)(wg0);     pwb0 = *(const float4*)(wg0 + 4);
    pwa1 = *(const float4*)(wg1);     pwb1 = *(const float4*)(wg1 + 4);
    pwa2 = *(const float4*)(wg2);     pwb2 = *(const float4*)(wg2 + 4);

    const int ko = l4 * 8;
    const int bo = (wv*16 + l15) * 40 + ko;

    for (int kt = 0; kt < NSTEP; ++kt) {
        __syncthreads();
        // ---- write phase: split regs -> LDS (chunk kt) ----
        {   // x slot 0
            float e[8] = {pxa0.x,pxa0.y,pxa0.z,pxa0.w,pxb0.x,pxb0.y,pxb0.z,pxb0.w};
            s16x8 v0, v1, v2;
            #pragma unroll
            for (int d = 0; d < 8; ++d) {
                unsigned short h0,h1,h2; split3(e[d],h0,h1,h2);
                v0[d]=(short)h0; v1[d]=(short)h1; v2[d]=(short)h2;
            }
            const int base = xr0*40 + xk;
            *(s16x8*)(sx + base)           = v0;
            *(s16x8*)(sx + 128*40 + base)  = v1;
            *(s16x8*)(sx + 256*40 + base)  = v2;
        }
        {   // x slot 1
            float e[8] = {pxa1.x,pxa1.y,pxa1.z,pxa1.w,pxb1.x,pxb1.y,pxb1.z,pxb1.w};
            s16x8 v0, v1, v2;
            #pragma unroll
            for (int d = 0; d < 8; ++d) {
                unsigned short h0,h1,h2; split3(e[d],h0,h1,h2);
                v0[d]=(short)h0; v1[d]=(short)h1; v2[d]=(short)h2;
            }
            const int base = xr1*40 + xk;
            *(s16x8*)(sx + base)           = v0;
            *(s16x8*)(sx + 128*40 + base)  = v1;
            *(s16x8*)(sx + 256*40 + base)  = v2;
        }
        {   // Wq (rows 0/64/128 + n)
            float e[8] = {pwa0.x,pwa0.y,pwa0.z,pwa0.w,pwb0.x,pwb0.y,pwb0.z,pwb0.w};
            s16x8 v0, v1, v2;
            #pragma unroll
            for (int d = 0; d < 8; ++d) {
                unsigned short h0,h1,h2; split3(e[d],h0,h1,h2);
                v0[d]=(short)h0; v1[d]=(short)h1; v2[d]=(short)h2;
            }
            const int base = wn*40 + xk;
            *(s16x8*)(sw + base)           = v0;
            *(s16x8*)(sw + 64*40 + base)   = v1;
            *(s16x8*)(sw + 128*40 + base)  = v2;
        }
        {   // Wk (rows 192/256/320 + n)
            float e[8] = {pwa1.x,pwa1.y,pwa1.z,pwa1.w,pwb1.x,pwb1.y,pwb1.z,pwb1.w};
            s16x8 v0, v1, v2;
            #pragma unroll
            for (int d = 0; d < 8; ++d) {
                unsigned short h0,h1,h2; split3(e[d],h0,h1,h2);
                v0[d]=(short)h0; v1[d]=(short)h1; v2[d]=(short)h2;
            }
            const int base = wn*40 + xk;
            *(s16x8*)(sw + 192*40 + base)  = v0;
            *(s16x8*)(sw + 256*40 + base)  = v1;
            *(s16x8*)(sw + 320*40 + base)  = v2;
        }
        {   // Wv (rows 384/448 + n) — 2 splits suffice (linear path)
            float e[8] = {pwa2.x,pwa2.y,pwa2.z,pwa2.w,pwb2.x,pwb2.y,pwb2.z,pwb2.w};
            s16x8 v0, v1;
            #pragma unroll
            for (int d = 0; d < 8; ++d) {
                unsigned short h0 = f2bf(e[d]);
                unsigned short h1 = f2bf(e[d] - bf2f(h0));
                v0[d]=(short)h0; v1[d]=(short)h1;
            }
            const int base = wn*40 + xk;
            *(s16x8*)(sw + 384*40 + base)  = v0;
            *(s16x8*)(sw + 448*40 + base)  = v1;
        }
        __syncthreads();

        // ---- prefetch chunk kt+1 (overlaps MFMA below) ----
        if (kt + 1 < NSTEP) {
            const int k0 = (kt + 1) * BK;
            pxa0 = *(const float4*)(xg0 + k0); pxb0 = *(const float4*)(xg0 + k0 + 4);
            pxa1 = *(const float4*)(xg1 + k0); pxb1 = *(const float4*)(xg1 + k0 + 4);
            pwa0 = *(const float4*)(wg0 + k0); pwb0 = *(const float4*)(wg0 + k0 + 4);
            pwa1 = *(const float4*)(wg1 + k0); pwb1 = *(const float4*)(wg1 + k0 + 4);
            pwa2 = *(const float4*)(wg2 + k0); pwb2 = *(const float4*)(wg2 + k0 + 4);
        }

        // ---- B-fragments for this wave's cols ----
        s16x8 Bq0 = *(const s16x8*)(sw + bo);
        s16x8 Bq1 = *(const s16x8*)(sw + 64*40  + bo);
        s16x8 Bq2 = *(const s16x8*)(sw + 128*40 + bo);
        s16x8 Bk0 = *(const s16x8*)(sw + 192*40 + bo);
        s16x8 Bk1 = *(const s16x8*)(sw + 256*40 + bo);
        s16x8 Bk2 = *(const s16x8*)(sw + 320*40 + bo);
        s16x8 Bv0 = *(const s16x8*)(sw + 384*40 + bo);
        s16x8 Bv1 = *(const s16x8*)(sw + 448*40 + bo);

        // ---- MFMA: 8 row-frags x (q:6, k:6, v:3 products) ----
        #pragma unroll
        for (int fb = 0; fb < 8; ++fb) {
            const int ab = (fb*16 + l15)*40 + ko;
            s16x8 a0 = *(const s16x8*)(sx + ab);
            s16x8 a1 = *(const s16x8*)(sx + 128*40 + ab);
            s16x8 a2 = *(const s16x8*)(sx + 256*40 + ab);
            f32x4 cq = acc[fb][0];
            cq = MFMA_BF16(a2, Bq0, cq);
            cq = MFMA_BF16(a1, Bq1, cq);
            cq = MFMA_BF16(a0, Bq2, cq);
            cq = MFMA_BF16(a1, Bq0, cq);
            cq = MFMA_BF16(a0, Bq1, cq);
            cq = MFMA_BF16(a0, Bq0, cq);
            acc[fb][0] = cq;
            f32x4 ck = acc[fb][1];
            ck = MFMA_BF16(a2, Bk0, ck);
            ck = MFMA_BF16(a1, Bk1, ck);
            ck = MFMA_BF16(a0, Bk2, ck);
            ck = MFMA_BF16(a1, Bk0, ck);
            ck = MFMA_BF16(a0, Bk1, ck);
            ck = MFMA_BF16(a0, Bk0, ck);
            acc[fb][1] = ck;
            f32x4 cv = acc[fb][2];
            cv = MFMA_BF16(a1, Bv0, cv);
            cv = MFMA_BF16(a0, Bv1, cv);
            cv = MFMA_BF16(a0, Bv0, cv);
            acc[fb][2] = cv;
        }
    }

    // ---- attention (fp32 accs -> LDS, two 16-token halves) ----
    __syncthreads();
    float* qa = (float*)smem;          // [64][68]
    float* ka = qa + 4352;
    float* va = qa + 8704;

    const int ar  = tid >> 2;          // 0..63 = t*16 + jj
    const int t_  = ar >> 4;
    const int jj  = ar & 15;
    const int sub = tid & 3;
    const int cw  = wv*16 + l15;

    #pragma unroll
    for (int hh = 0; hh < 2; ++hh) {
        #pragma unroll
        for (int m = 0; m < 4; ++m) {
            const int fb = hh + 2*m;          // rows r=fb*16+i -> t=m, j=16*hh+i
            const int rb = m*16 + l4*4;
            #pragma unroll
            for (int rg = 0; rg < 4; ++rg) {
                qa[(rb+rg)*68 + cw] = acc[fb][0][rg];
                ka[(rb+rg)*68 + cw] = acc[fb][1][rg];
                va[(rb+rg)*68 + cw] = acc[fb][2][rg];
            }
        }
        __syncthreads();

        const float* qp = qa + ar*68 + sub*16;
        float4 q0 = *(const float4*)(qp);
        float4 q1 = *(const float4*)(qp + 4);
        float4 q2 = *(const float4*)(qp + 8);
        float4 q3 = *(const float4*)(qp + 12);
        float sc[4];
        #pragma unroll
        for (int ss = 0; ss < 4; ++ss) {
            const float* kp = ka + (ss*16 + jj)*68 + sub*16;
            float4 k0 = *(const float4*)(kp);
            float4 k1 = *(const float4*)(kp + 4);
            float4 k2 = *(const float4*)(kp + 8);
            float4 k3 = *(const float4*)(kp + 12);
            float p = q0.x*k0.x + q0.y*k0.y + q0.z*k0.z + q0.w*k0.w
                    + q1.x*k1.x + q1.y*k1.y + q1.z*k1.z + q1.w*k1.w
                    + q2.x*k2.x + q2.y*k2.y + q2.z*k2.z + q2.w*k2.w
                    + q3.x*k3.x + q3.y*k3.y + q3.z*k3.z + q3.w*k3.w;
            p += __shfl_xor(p, 1);
            p += __shfl_xor(p, 2);
            sc[ss] = p;    // full 64-dot; spike <=> (dot/8)/2 >= 1 <=> dot >= 16
        }
        float o[16];
        #pragma unroll
        for (int d = 0; d < 16; ++d) o[d] = 0.f;
        #pragma unroll
        for (int ss = 0; ss < 4; ++ss) {
            if (sc[ss] >= 16.0f) {
                const float* vp = va + (ss*16 + jj)*68 + sub*16;
                float4 va0 = *(const float4*)(vp);
                float4 va1 = *(const float4*)(vp + 4);
                float4 va2 = *(const float4*)(vp + 8);
                float4 va3 = *(const float4*)(vp + 12);
                o[0]+=va0.x; o[1]+=va0.y; o[2]+=va0.z;  o[3]+=va0.w;
                o[4]+=va1.x; o[5]+=va1.y; o[6]+=va1.z;  o[7]+=va1.w;
                o[8]+=va2.x; o[9]+=va2.y; o[10]+=va2.z; o[11]+=va2.w;
                o[12]+=va3.x;o[13]+=va3.y;o[14]+=va3.z; o[15]+=va3.w;
            }
        }
        float* op = outp + ((size_t)t_*PTOT + p0 + hh*16 + jj)*CCC + h*64 + sub*16;
        *(float4*)(op)      = make_float4(o[0],o[1],o[2],o[3]);
        *(float4*)(op + 4)  = make_float4(o[4],o[5],o[6],o[7]);
        *(float4*)(op + 8)  = make_float4(o[8],o[9],o[10],o[11]);
        *(float4*)(op + 12) = make_float4(o[12],o[13],o[14],o[15]);
        __syncthreads();
    }
}

// ---------------------------------------------------------------------------
// k2: out = A @ Wo^T + bo  (65536 x 512, K=512), fp32 VALU, 128x128 tiles.
// ---------------------------------------------------------------------------
__global__ __launch_bounds__(256, 2)
void k2_gemm(const float* __restrict__ A, const float* __restrict__ W,
             const float* __restrict__ b, float* __restrict__ out)
{
    __shared__ __align__(16) float sa[BK][128+4];
    __shared__ __align__(16) float sb[BK][128+4];

    const int tid = threadIdx.x;
    const int bn  = (blockIdx.x & 3) * 128;
    const size_t bm = (size_t)(blockIdx.x >> 2) * 128;
    const int tx = tid & 15, ty = tid >> 4;

    float acc[8][8];
    #pragma unroll
    for (int ci = 0; ci < 8; ++ci) {
        const float bb = b[bn + tx*8 + ci];
        #pragma unroll
        for (int ri = 0; ri < 8; ++ri) acc[ri][ci] = bb;
    }

    const float* asrc[4]; const float* bsrc[4]; int sr[4], sk4[4];
    #pragma unroll
    for (int jj = 0; jj < 4; ++jj) {
        const int flat = tid + 256*jj;
        const int r = flat >> 3, c4 = flat & 7;
        asrc[jj] = A + (bm + r)*CCC + c4*4;
        bsrc[jj] = W + (size_t)(bn + r)*CCC + c4*4;
        sr[jj] = r; sk4[jj] = c4*4;
    }

    for (int kt = 0; kt < CCC/BK; ++kt) {
        const int k0 = kt*BK;
        __syncthreads();
        #pragma unroll
        for (int jj = 0; jj < 4; ++jj) {
            const float4 ta = *(const float4*)(asrc[jj] + k0);
            sa[sk4[jj]+0][sr[jj]] = ta.x;
            sa[sk4[jj]+1][sr[jj]] = ta.y;
            sa[sk4[jj]+2][sr[jj]] = ta.z;
            sa[sk4[jj]+3][sr[jj]] = ta.w;
            const float4 tb = *(const float4*)(bsrc[jj] + k0);
            sb[sk4[jj]+0][sr[jj]] = tb.x;
            sb[sk4[jj]+1][sr[jj]] = tb.y;
            sb[sk4[jj]+2][sr[jj]] = tb.z;
            sb[sk4[jj]+3][sr[jj]] = tb.w;
        }
        __syncthreads();

        #pragma unroll 4
        for (int kk = 0; kk < BK; ++kk) {
            const float4 a0 = *(const float4*)&sa[kk][ty*8];
            const float4 a1 = *(const float4*)&sa[kk][ty*8+4];
            const float4 b0 = *(const float4*)&sb[kk][tx*8];
            const float4 b1 = *(const float4*)&sb[kk][tx*8+4];
            const float arr[8] = {a0.x,a0.y,a0.z,a0.w,a1.x,a1.y,a1.z,a1.w};
            const float brr[8] = {b0.x,b0.y,b0.z,b0.w,b1.x,b1.y,b1.z,b1.w};
            #pragma unroll
            for (int ri = 0; ri < 8; ++ri)
                #pragma unroll
                for (int ci = 0; ci < 8; ++ci)
                    acc[ri][ci] += arr[ri]*brr[ci];
        }
    }

    #pragma unroll
    for (int ri = 0; ri < 8; ++ri) {
        const size_t row = bm + ty*8 + ri;
        float* op = out + row*CCC + bn + tx*8;
        *(float4*)op     = make_float4(acc[ri][0],acc[ri][1],acc[ri][2],acc[ri][3]);
        *(float4*)(op+4) = make_float4(acc[ri][4],acc[ri][5],acc[ri][6],acc[ri][7]);
    }
}

// ---------------------------------------------------------------------------
extern "C" void kernel_launch(void* const* d_in, const int* in_sizes, int n_in,
                              void* d_out, int out_size, void* d_ws, size_t ws_size,
                              hipStream_t stream)
{
    const float* x  = (const float*)d_in[0];
    const float* Wq = (const float*)d_in[1];
    const float* bq = (const float*)d_in[2];
    const float* Wk = (const float*)d_in[3];
    const float* bk = (const float*)d_in[4];
    const float* Wv = (const float*)d_in[5];
    const float* bv = (const float*)d_in[6];
    const float* Wo = (const float*)d_in[7];
    const float* bo = (const float*)d_in[8];

    float* outp = (float*)d_ws;        // pre-Wo activation: 134 MB
    float* out  = (float*)d_out;

    hipLaunchKernelGGL(k1_mfma, dim3((PTOT/32)*HHH), dim3(256), 0, stream,
                       x, Wq, bq, Wk, bk, Wv, bv, outp);
    hipLaunchKernelGGL(k2_gemm, dim3((MROWS/128)*(CCC/128)), dim3(256), 0, stream,
                       outp, Wo, bo, out);
}

// Round 3
// 332.231 us; speedup vs baseline: 4.8840x; 2.7363x over previous
//
#include <hip/hip_runtime.h>

#define PTOT  16384
#define CCC   512
#define HHH   8
#define NSTEP 16                 /* 512/32 k-steps */

typedef __attribute__((ext_vector_type(4))) float f32x4;
typedef _Float16 half_t;
typedef __attribute__((ext_vector_type(8))) _Float16 f16x8;

#define MFMA_F16(a,b,c) __builtin_amdgcn_mfma_f32_16x16x32_f16(a,b,c,0,0,0)

// ---- ws plane layout (half elements) ----
// xh:0  xl:+33554432  acth:+67108864  W planes at +100663296:
//   qh, ql, kh, kl, vh, oh  (each 262144)
#define XH_OFF   ((size_t)0)
#define XL_OFF   ((size_t)33554432)
#define ACT_OFF  ((size_t)67108864)
#define W_OFF    ((size_t)100663296)
#define WPL      ((size_t)262144)

// blocked fp16 plane: 16 rows x 32 cols = 1KB blocks; within block:
// [(col>>3)&3][row&15][col&7]  -> one MFMA frag == one contiguous 1KB block
__device__ __forceinline__ size_t blk_off(int row, int col) {
    return ((size_t)((row >> 4) * 16 + (col >> 5)) << 9)
         + (size_t)(((((col >> 3) & 3) * 16) + (row & 15)) << 3) + (col & 7);
}

// ---------------------------------------------------------------------------
// k0: split fp32 -> fp16 hi/lo planes in blocked layout.
// units of 8 elems; x: 4194304 units, then 4 W mats x 32768 units.
// ---------------------------------------------------------------------------
__global__ void k0_split(const float* __restrict__ x,
                         const float* __restrict__ Wq, const float* __restrict__ Wk,
                         const float* __restrict__ Wv, const float* __restrict__ Wo,
                         half_t* __restrict__ ws)
{
    const int u = blockIdx.x * 256 + threadIdx.x;
    const float* src;
    half_t *dh, *dl;
    int gr, v;
    if (u < 4194304) {
        gr = u >> 10; v = u & 1023;
        src = x; dh = ws + XH_OFF; dl = ws + XL_OFF;
    } else {
        const int u2 = u - 4194304;
        const int mat = u2 >> 15, r = u2 & 32767;
        gr = r >> 10; v = r & 1023;
        if      (mat == 0) { src = Wq; dh = ws + W_OFF;           dl = ws + W_OFF + WPL; }
        else if (mat == 1) { src = Wk; dh = ws + W_OFF + 2*WPL;   dl = ws + W_OFF + 3*WPL; }
        else if (mat == 2) { src = Wv; dh = ws + W_OFF + 4*WPL;   dl = nullptr; }
        else               { src = Wo; dh = ws + W_OFF + 5*WPL;   dl = nullptr; }
    }
    const int ktc = v >> 6, chunk = (v >> 4) & 3, i = v & 15;
    const int row = gr * 16 + i, col = ktc * 32 + chunk * 8;

    const float4 a = *(const float4*)(src + (size_t)row * CCC + col);
    const float4 b = *(const float4*)(src + (size_t)row * CCC + col + 4);
    const float e[8] = {a.x, a.y, a.z, a.w, b.x, b.y, b.z, b.w};
    f16x8 vh8, vl8;
    #pragma unroll
    for (int d = 0; d < 8; ++d) {
        const half_t hi = (half_t)e[d];
        const half_t lo = (half_t)(e[d] - (float)hi);
        vh8[d] = hi; vl8[d] = lo;
    }
    const size_t off = blk_off(row, col);
    *(f16x8*)(dh + off) = vh8;
    if (dl) *(f16x8*)(dl + off) = vl8;
}

// ---------------------------------------------------------------------------
// k1: QKV projection via fp16x2 MFMA (Q:3,K:3,V:1 products) + spiking attn.
// Grid 4096 blocks x 256 thr. Block: 32 tokens x 4 t = 128 rows, 1 head.
// LDS: 2 x 36KB staging buffers (X: 16 x 1KB frag slots, W: 20 x 1KB),
// overlaid by epilogue qa/ka/va [64][68] f32 (52224B). Total 73728B.
// ---------------------------------------------------------------------------
__global__ __launch_bounds__(256, 2)
void k1_mfma(const half_t* __restrict__ ws,
             const float* __restrict__ bq, const float* __restrict__ bk,
             const float* __restrict__ bv,
             half_t* __restrict__ acth)
{
    __shared__ __align__(16) char smem[73728];

    const int tid  = threadIdx.x;
    const int lane = tid & 63;
    const int wv   = tid >> 6;
    const int wr   = wv >> 1;          // row half (0..1)
    const int wc   = wv & 1;           // col half (0..1)
    const int l15  = lane & 15;
    const int l4   = lane >> 4;

    // XCD-aware decode: same-token blocks (all 8 heads) share an XCD's L2
    const int xcd = blockIdx.x & 7;
    const int rest = blockIdx.x >> 3;
    const int h   = rest & 7;
    const int tg  = rest >> 3;                 // 0..63
    const int p0  = (tg * 8 + xcd) * 32;       // token base

    // ---- staging issue list: 36 issues/kt, 9 per wave ----
    const half_t* gb[9]; int lo_[9];
    #pragma unroll
    for (int ii = 0; ii < 9; ++ii) {
        const int i = wv * 9 + ii;
        size_t eoff; int loff;
        if (i < 16) {                       // X frags: slot = pl*8+fb
            const int pl = i >> 3, fb = i & 7;
            const int grow = (((fb >> 1) * PTOT) + p0 + ((fb & 1) * 16)) >> 4;
            eoff = (pl ? XL_OFF : XH_OFF) + ((size_t)grow << 13) + lane * 8;
            loff = i * 1024;
        } else {                            // W frags: slot = plw*4+cf
            const int s = i - 16, plw = s >> 2, cf = s & 3;
            const int grow = h * 4 + cf;
            eoff = W_OFF + (size_t)plw * WPL + ((size_t)grow << 13) + lane * 8;
            loff = 16384 + s * 1024;
        }
        gb[ii] = ws + eoff;
        lo_[ii] = loff;
    }

#define K1_STAGE(buf, kt) do {                                                  \
    _Pragma("unroll")                                                           \
    for (int ii = 0; ii < 9; ++ii)                                              \
        __builtin_amdgcn_global_load_lds(                                       \
            (const __attribute__((address_space(1))) void*)(gb[ii] + (size_t)(kt) * 512), \
            (__attribute__((address_space(3))) void*)(smem + (buf) * 36864 + lo_[ii]),    \
            16, 0, 0);                                                          \
    } while (0)

    // ---- accumulators (bias init; C/D: col=lane&15, row=(lane>>4)*4+reg) ----
    f32x4 accQ[4][2], accK[4][2], accV[4][2];
    {
        const int c0 = h * 64 + wc * 32 + l15, c1 = c0 + 16;
        const float bq0 = bq[c0], bq1 = bq[c1];
        const float bk0 = bk[c0], bk1 = bk[c1];
        const float bv0 = bv[c0], bv1 = bv[c1];
        #pragma unroll
        for (int rf = 0; rf < 4; ++rf) {
            accQ[rf][0] = f32x4{bq0, bq0, bq0, bq0};
            accQ[rf][1] = f32x4{bq1, bq1, bq1, bq1};
            accK[rf][0] = f32x4{bk0, bk0, bk0, bk0};
            accK[rf][1] = f32x4{bk1, bk1, bk1, bk1};
            accV[rf][0] = f32x4{bv0, bv0, bv0, bv0};
            accV[rf][1] = f32x4{bv1, bv1, bv1, bv1};
        }
    }

    K1_STAGE(0, 0);
    asm volatile("s_waitcnt vmcnt(0)" ::: "memory");
    __syncthreads();

    for (int kt = 0; kt < NSTEP; ++kt) {
        const int cur = kt & 1;
        if (kt + 1 < NSTEP) K1_STAGE(cur ^ 1, kt + 1);

        const char* bp = smem + cur * 36864;
        // B frags for this wave's column half
        f16x8 Bqh[2], Bql[2], Bkh[2], Bkl[2], Bvh[2];
        #pragma unroll
        for (int c = 0; c < 2; ++c) {
            const int cf = wc * 2 + c;
            Bqh[c] = *(const f16x8*)(bp + 16384 + (0*4 + cf) * 1024 + lane * 16);
            Bql[c] = *(const f16x8*)(bp + 16384 + (1*4 + cf) * 1024 + lane * 16);
            Bkh[c] = *(const f16x8*)(bp + 16384 + (2*4 + cf) * 1024 + lane * 16);
            Bkl[c] = *(const f16x8*)(bp + 16384 + (3*4 + cf) * 1024 + lane * 16);
            Bvh[c] = *(const f16x8*)(bp + 16384 + (4*4 + cf) * 1024 + lane * 16);
        }
        #pragma unroll
        for (int rf = 0; rf < 4; ++rf) {
            const int fb = wr * 4 + rf;
            const f16x8 Ah = *(const f16x8*)(bp + fb * 1024 + lane * 16);
            const f16x8 Al = *(const f16x8*)(bp + (8 + fb) * 1024 + lane * 16);
            #pragma unroll
            for (int c = 0; c < 2; ++c) {
                f32x4 q = accQ[rf][c];
                q = MFMA_F16(Ah, Bqh[c], q);
                q = MFMA_F16(Ah, Bql[c], q);
                q = MFMA_F16(Al, Bqh[c], q);
                accQ[rf][c] = q;
                f32x4 k = accK[rf][c];
                k = MFMA_F16(Ah, Bkh[c], k);
                k = MFMA_F16(Ah, Bkl[c], k);
                k = MFMA_F16(Al, Bkh[c], k);
                accK[rf][c] = k;
                accV[rf][c] = MFMA_F16(Ah, Bvh[c], accV[rf][c]);
            }
        }
        asm volatile("s_waitcnt vmcnt(0)" ::: "memory");
        __syncthreads();
    }

    // ---- attention epilogue (two token-half passes) ----
    float* qa = (float*)smem;            // [64][68]
    float* ka = qa + 4352;
    float* va = qa + 8704;

    const int ar  = tid >> 2;            // 0..63 = t*16 + jj
    const int t_  = ar >> 4;
    const int jj  = ar & 15;
    const int sub = tid & 3;

    #pragma unroll
    for (int hh = 0; hh < 2; ++hh) {
        // dump this pass's frags (token-half hh): in-wave rf = 2m+hh, t = 2wr+m
        #pragma unroll
        for (int m = 0; m < 2; ++m) {
            const int rf = 2 * m + hh;
            const int t  = 2 * wr + m;
            const int rb = t * 16 + l4 * 4;
            #pragma unroll
            for (int c = 0; c < 2; ++c) {
                const int cc = wc * 32 + c * 16 + l15;
                #pragma unroll
                for (int r = 0; r < 4; ++r) {
                    qa[(rb + r) * 68 + cc] = accQ[rf][c][r];
                    ka[(rb + r) * 68 + cc] = accK[rf][c][r];
                    va[(rb + r) * 68 + cc] = accV[rf][c][r];
                }
            }
        }
        __syncthreads();

        const float* qp = qa + ar * 68 + sub * 16;
        const float4 q0 = *(const float4*)(qp);
        const float4 q1 = *(const float4*)(qp + 4);
        const float4 q2 = *(const float4*)(qp + 8);
        const float4 q3 = *(const float4*)(qp + 12);
        float sc[4];
        #pragma unroll
        for (int ss = 0; ss < 4; ++ss) {
            const float* kp = ka + (ss * 16 + jj) * 68 + sub * 16;
            const float4 k0 = *(const float4*)(kp);
            const float4 k1 = *(const float4*)(kp + 4);
            const float4 k2 = *(const float4*)(kp + 8);
            const float4 k3 = *(const float4*)(kp + 12);
            float p = q0.x*k0.x + q0.y*k0.y + q0.z*k0.z + q0.w*k0.w
                    + q1.x*k1.x + q1.y*k1.y + q1.z*k1.z + q1.w*k1.w
                    + q2.x*k2.x + q2.y*k2.y + q2.z*k2.z + q2.w*k2.w
                    + q3.x*k3.x + q3.y*k3.y + q3.z*k3.z + q3.w*k3.w;
            p += __shfl_xor(p, 1);
            p += __shfl_xor(p, 2);
            sc[ss] = p;      // spike <=> (dot/8)/2 >= 1 <=> dot >= 16 (exact)
        }
        float o[16];
        #pragma unroll
        for (int d = 0; d < 16; ++d) o[d] = 0.f;
        #pragma unroll
        for (int ss = 0; ss < 4; ++ss) {
            if (sc[ss] >= 16.0f) {
                const float* vp = va + (ss * 16 + jj) * 68 + sub * 16;
                const float4 v0 = *(const float4*)(vp);
                const float4 v1 = *(const float4*)(vp + 4);
                const float4 v2 = *(const float4*)(vp + 8);
                const float4 v3 = *(const float4*)(vp + 12);
                o[0]+=v0.x; o[1]+=v0.y; o[2]+=v0.z;  o[3]+=v0.w;
                o[4]+=v1.x; o[5]+=v1.y; o[6]+=v1.z;  o[7]+=v1.w;
                o[8]+=v2.x; o[9]+=v2.y; o[10]+=v2.z; o[11]+=v2.w;
                o[12]+=v3.x;o[13]+=v3.y;o[14]+=v3.z; o[15]+=v3.w;
            }
        }
        // store act (fp16, blocked layout)
        f16x8 o0, o1;
        #pragma unroll
        for (int d = 0; d < 8; ++d) { o0[d] = (half_t)o[d]; o1[d] = (half_t)o[d + 8]; }
        const int grow = t_ * 1024 + (p0 >> 4) + hh;
        const int colb = h * 64 + sub * 16;
        const size_t cbase = ((size_t)(grow * 16 + (colb >> 5))) << 9;
        const int c0 = (colb >> 3) & 3;
        *(f16x8*)(acth + cbase + (size_t)((c0       * 16 + jj) << 3)) = o0;
        *(f16x8*)(acth + cbase + (size_t)(((c0 + 1) * 16 + jj) << 3)) = o1;
        __syncthreads();
    }
#undef K1_STAGE
}

// ---------------------------------------------------------------------------
// k2: out = act @ Wo^T + bo, fp16 MFMA (1 product). 128x128 tiles, K=512.
// ---------------------------------------------------------------------------
__global__ __launch_bounds__(256, 4)
void k2_gemm(const half_t* __restrict__ acth, const half_t* __restrict__ oh,
             const float* __restrict__ bo, float* __restrict__ out)
{
    __shared__ __align__(16) char smem[32768];

    const int tid  = threadIdx.x;
    const int lane = tid & 63;
    const int wv   = tid >> 6;
    const int wr   = wv >> 1, wc = wv & 1;
    const int l15  = lane & 15, l4 = lane >> 4;
    const int bn   = (blockIdx.x & 3) * 128;
    const int bm   = (blockIdx.x >> 2) * 128;

    const half_t* gb[4]; int lo_[4];
    #pragma unroll
    for (int ii = 0; ii < 4; ++ii) {
        const int i = wv * 4 + ii;
        if (i < 8) {       // A frags
            const int grow = (bm >> 4) + i;
            gb[ii] = acth + ((size_t)grow << 13) + lane * 8;
            lo_[ii] = i * 1024;
        } else {           // B frags
            const int fb = i - 8;
            const int grow = (bn >> 4) + fb;
            gb[ii] = oh + ((size_t)grow << 13) + lane * 8;
            lo_[ii] = 8192 + fb * 1024;
        }
    }

#define K2_STAGE(buf, kt) do {                                                  \
    _Pragma("unroll")                                                           \
    for (int ii = 0; ii < 4; ++ii)                                              \
        __builtin_amdgcn_global_load_lds(                                       \
            (const __attribute__((address_space(1))) void*)(gb[ii] + (size_t)(kt) * 512), \
            (__attribute__((address_space(3))) void*)(smem + (buf) * 16384 + lo_[ii]),    \
            16, 0, 0);                                                          \
    } while (0)

    f32x4 acc[4][4];
    #pragma unroll
    for (int rf = 0; rf < 4; ++rf)
        #pragma unroll
        for (int cf = 0; cf < 4; ++cf) acc[rf][cf] = f32x4{0.f, 0.f, 0.f, 0.f};

    K2_STAGE(0, 0);
    asm volatile("s_waitcnt vmcnt(0)" ::: "memory");
    __syncthreads();

    for (int kt = 0; kt < NSTEP; ++kt) {
        const int cur = kt & 1;
        if (kt + 1 < NSTEP) K2_STAGE(cur ^ 1, kt + 1);
        const char* bp = smem + cur * 16384;
        f16x8 B[4];
        #pragma unroll
        for (int cf = 0; cf < 4; ++cf)
            B[cf] = *(const f16x8*)(bp + 8192 + (wc * 4 + cf) * 1024 + lane * 16);
        #pragma unroll
        for (int rf = 0; rf < 4; ++rf) {
            const f16x8 A = *(const f16x8*)(bp + (wr * 4 + rf) * 1024 + lane * 16);
            #pragma unroll
            for (int cf = 0; cf < 4; ++cf)
                acc[rf][cf] = MFMA_F16(A, B[cf], acc[rf][cf]);
        }
        asm volatile("s_waitcnt vmcnt(0)" ::: "memory");
        __syncthreads();
    }

    float bo4[4];
    #pragma unroll
    for (int cf = 0; cf < 4; ++cf) bo4[cf] = bo[bn + (wc * 4 + cf) * 16 + l15];

    #pragma unroll
    for (int rf = 0; rf < 4; ++rf) {
        const int row0 = bm + (wr * 4 + rf) * 16 + l4 * 4;
        #pragma unroll
        for (int cf = 0; cf < 4; ++cf) {
            const int col = bn + (wc * 4 + cf) * 16 + l15;
            #pragma unroll
            for (int r = 0; r < 4; ++r)
                out[(size_t)(row0 + r) * CCC + col] = acc[rf][cf][r] + bo4[cf];
        }
    }
#undef K2_STAGE
}

// ---------------------------------------------------------------------------
extern "C" void kernel_launch(void* const* d_in, const int* in_sizes, int n_in,
                              void* d_out, int out_size, void* d_ws, size_t ws_size,
                              hipStream_t stream)
{
    const float* x  = (const float*)d_in[0];
    const float* Wq = (const float*)d_in[1];
    const float* bq = (const float*)d_in[2];
    const float* Wk = (const float*)d_in[3];
    const float* bk = (const float*)d_in[4];
    const float* Wv = (const float*)d_in[5];
    const float* bv = (const float*)d_in[6];
    const float* Wo = (const float*)d_in[7];
    const float* bo = (const float*)d_in[8];

    half_t* ws   = (half_t*)d_ws;
    half_t* acth = ws + ACT_OFF;
    float*  out  = (float*)d_out;

    hipLaunchKernelGGL(k0_split, dim3(16896), dim3(256), 0, stream,
                       x, Wq, Wk, Wv, Wo, ws);
    hipLaunchKernelGGL(k1_mfma, dim3(4096), dim3(256), 0, stream,
                       ws, bq, bk, bv, acth);
    hipLaunchKernelGGL(k2_gemm, dim3(2048), dim3(256), 0, stream,
                       acth, ws + W_OFF + 5*WPL, bo, out);
}

// Round 4
// 317.786 us; speedup vs baseline: 5.1060x; 1.0455x over previous
//
#include <hip/hip_runtime.h>

#define PTOT  16384
#define CCC   512
#define HHH   8
#define NSTEP 16                 /* 512/32 k-steps */

typedef __attribute__((ext_vector_type(4))) float f32x4;
typedef _Float16 half_t;
typedef __attribute__((ext_vector_type(8))) _Float16 f16x8;

#define MFMA_F16(a,b,c) __builtin_amdgcn_mfma_f32_16x16x32_f16(a,b,c,0,0,0)

// ---- ws plane layout (half elements) ----
#define XH_OFF   ((size_t)0)
#define XL_OFF   ((size_t)33554432)
#define ACT_OFF  ((size_t)67108864)
#define W_OFF    ((size_t)100663296)
#define WPL      ((size_t)262144)

// blocked fp16 plane: 16 rows x 32 cols = 1KB blocks; within block:
// [(col>>3)&3][row&15][col&7]  -> one MFMA frag == one contiguous 1KB block
__device__ __forceinline__ size_t blk_off(int row, int col) {
    return ((size_t)((row >> 4) * 16 + (col >> 5)) << 9)
         + (size_t)(((((col >> 3) & 3) * 16) + (row & 15)) << 3) + (col & 7);
}

// ---------------------------------------------------------------------------
// k0: split fp32 -> fp16 hi/lo planes in blocked layout.
// ---------------------------------------------------------------------------
__global__ void k0_split(const float* __restrict__ x,
                         const float* __restrict__ Wq, const float* __restrict__ Wk,
                         const float* __restrict__ Wv, const float* __restrict__ Wo,
                         half_t* __restrict__ ws)
{
    const int u = blockIdx.x * 256 + threadIdx.x;
    const float* src;
    half_t *dh, *dl;
    int gr, v;
    if (u < 4194304) {
        gr = u >> 10; v = u & 1023;
        src = x; dh = ws + XH_OFF; dl = ws + XL_OFF;
    } else {
        const int u2 = u - 4194304;
        const int mat = u2 >> 15, r = u2 & 32767;
        gr = r >> 10; v = r & 1023;
        if      (mat == 0) { src = Wq; dh = ws + W_OFF;           dl = ws + W_OFF + WPL; }
        else if (mat == 1) { src = Wk; dh = ws + W_OFF + 2*WPL;   dl = ws + W_OFF + 3*WPL; }
        else if (mat == 2) { src = Wv; dh = ws + W_OFF + 4*WPL;   dl = nullptr; }
        else               { src = Wo; dh = ws + W_OFF + 5*WPL;   dl = nullptr; }
    }
    const int ktc = v >> 6, chunk = (v >> 4) & 3, i = v & 15;
    const int row = gr * 16 + i, col = ktc * 32 + chunk * 8;

    const float4 a = *(const float4*)(src + (size_t)row * CCC + col);
    const float4 b = *(const float4*)(src + (size_t)row * CCC + col + 4);
    const float e[8] = {a.x, a.y, a.z, a.w, b.x, b.y, b.z, b.w};
    f16x8 vh8, vl8;
    #pragma unroll
    for (int d = 0; d < 8; ++d) {
        const half_t hi = (half_t)e[d];
        const half_t lo = (half_t)(e[d] - (float)hi);
        vh8[d] = hi; vl8[d] = lo;
    }
    const size_t off = blk_off(row, col);
    *(f16x8*)(dh + off) = vh8;
    if (dl) *(f16x8*)(dl + off) = vl8;
}

// ---------------------------------------------------------------------------
// k1: QKV projection via fp16x2 MFMA (Q:3,K:3,V:1) + spiking attn.
// Counted-vmcnt 2-phase pipeline (T3/T4): stage(kt+1) stays in flight across
// raw s_barriers; vmcnt(9) gates only stage(kt) completion.
// ---------------------------------------------------------------------------
__global__ __launch_bounds__(256, 2)
void k1_mfma(const half_t* __restrict__ ws,
             const float* __restrict__ bq, const float* __restrict__ bk,
             const float* __restrict__ bv,
             half_t* __restrict__ acth)
{
    __shared__ __align__(16) char smem[73728];

    const int tid  = threadIdx.x;
    const int lane = tid & 63;
    const int wv   = tid >> 6;
    const int wr   = wv >> 1;
    const int wc   = wv & 1;
    const int l15  = lane & 15;
    const int l4   = lane >> 4;

    const int xcd = blockIdx.x & 7;
    const int rest = blockIdx.x >> 3;
    const int h   = rest & 7;
    const int tg  = rest >> 3;
    const int p0  = (tg * 8 + xcd) * 32;

    // ---- staging issue list: 9 gload_lds per wave per kt ----
    const half_t* gb[9]; int lo_[9];
    #pragma unroll
    for (int ii = 0; ii < 9; ++ii) {
        const int i = wv * 9 + ii;
        size_t eoff; int loff;
        if (i < 16) {
            const int pl = i >> 3, fb = i & 7;
            const int grow = (((fb >> 1) * PTOT) + p0 + ((fb & 1) * 16)) >> 4;
            eoff = (pl ? XL_OFF : XH_OFF) + ((size_t)grow << 13) + lane * 8;
            loff = i * 1024;
        } else {
            const int s = i - 16, plw = s >> 2, cf = s & 3;
            const int grow = h * 4 + cf;
            eoff = W_OFF + (size_t)plw * WPL + ((size_t)grow << 13) + lane * 8;
            loff = 16384 + s * 1024;
        }
        gb[ii] = ws + eoff;
        lo_[ii] = loff;
    }

#define K1_STAGE(buf, kt) do {                                                  \
    _Pragma("unroll")                                                           \
    for (int ii = 0; ii < 9; ++ii)                                              \
        __builtin_amdgcn_global_load_lds(                                       \
            (const __attribute__((address_space(1))) void*)(gb[ii] + (size_t)(kt) * 512), \
            (__attribute__((address_space(3))) void*)(smem + (buf) * 36864 + lo_[ii]),    \
            16, 0, 0);                                                          \
    } while (0)

    // ---- accumulators (bias init) ----
    f32x4 accQ[4][2], accK[4][2], accV[4][2];
    {
        const int c0 = h * 64 + wc * 32 + l15, c1 = c0 + 16;
        const float bq0 = bq[c0], bq1 = bq[c1];
        const float bk0 = bk[c0], bk1 = bk[c1];
        const float bv0 = bv[c0], bv1 = bv[c1];
        #pragma unroll
        for (int rf = 0; rf < 4; ++rf) {
            accQ[rf][0] = f32x4{bq0, bq0, bq0, bq0};
            accQ[rf][1] = f32x4{bq1, bq1, bq1, bq1};
            accK[rf][0] = f32x4{bk0, bk0, bk0, bk0};
            accK[rf][1] = f32x4{bk1, bk1, bk1, bk1};
            accV[rf][0] = f32x4{bv0, bv0, bv0, bv0};
            accV[rf][1] = f32x4{bv1, bv1, bv1, bv1};
        }
    }

    K1_STAGE(0, 0);

    #pragma unroll
    for (int kt = 0; kt < NSTEP; ++kt) {
        const int cur = kt & 1;
        if (kt + 1 < NSTEP) {
            K1_STAGE(cur ^ 1, kt + 1);
            asm volatile("s_waitcnt vmcnt(9)" ::: "memory");   // stage(kt) landed; 9 new in flight
        } else {
            asm volatile("s_waitcnt vmcnt(0)" ::: "memory");
        }
        __builtin_amdgcn_sched_barrier(0);
        __builtin_amdgcn_s_barrier();          // all waves' stage(kt) complete

        const char* bp = smem + cur * 36864;
        f16x8 Bqh[2], Bql[2], Bkh[2], Bkl[2], Bvh[2];
        #pragma unroll
        for (int c = 0; c < 2; ++c) {
            const int cf = wc * 2 + c;
            Bqh[c] = *(const f16x8*)(bp + 16384 + (0*4 + cf) * 1024 + lane * 16);
            Bql[c] = *(const f16x8*)(bp + 16384 + (1*4 + cf) * 1024 + lane * 16);
            Bkh[c] = *(const f16x8*)(bp + 16384 + (2*4 + cf) * 1024 + lane * 16);
            Bkl[c] = *(const f16x8*)(bp + 16384 + (3*4 + cf) * 1024 + lane * 16);
            Bvh[c] = *(const f16x8*)(bp + 16384 + (4*4 + cf) * 1024 + lane * 16);
        }
        #pragma unroll
        for (int rf = 0; rf < 4; ++rf) {
            const int fb = wr * 4 + rf;
            const f16x8 Ah = *(const f16x8*)(bp + fb * 1024 + lane * 16);
            const f16x8 Al = *(const f16x8*)(bp + (8 + fb) * 1024 + lane * 16);
            #pragma unroll
            for (int c = 0; c < 2; ++c) {
                f32x4 q = accQ[rf][c];
                q = MFMA_F16(Ah, Bqh[c], q);
                q = MFMA_F16(Ah, Bql[c], q);
                q = MFMA_F16(Al, Bqh[c], q);
                accQ[rf][c] = q;
                f32x4 k = accK[rf][c];
                k = MFMA_F16(Ah, Bkh[c], k);
                k = MFMA_F16(Ah, Bkl[c], k);
                k = MFMA_F16(Al, Bkh[c], k);
                accK[rf][c] = k;
                accV[rf][c] = MFMA_F16(Ah, Bvh[c], accV[rf][c]);
            }
        }
        asm volatile("s_waitcnt lgkmcnt(0)" ::: "memory");  // my reads of buf[cur] done
        __builtin_amdgcn_s_barrier();          // everyone done reading buf[cur]
        __builtin_amdgcn_sched_barrier(0);
    }

    // ---- attention epilogue ----
    float* qa = (float*)smem;            // [64][68]
    float* ka = qa + 4352;
    float* va = qa + 8704;

    const int ar  = tid >> 2;
    const int t_  = ar >> 4;
    const int jj  = ar & 15;
    const int sub = tid & 3;

    #pragma unroll
    for (int hh = 0; hh < 2; ++hh) {
        #pragma unroll
        for (int m = 0; m < 2; ++m) {
            const int rf = 2 * m + hh;
            const int t  = 2 * wr + m;
            const int rb = t * 16 + l4 * 4;
            #pragma unroll
            for (int c = 0; c < 2; ++c) {
                const int cc = wc * 32 + c * 16 + l15;
                #pragma unroll
                for (int r = 0; r < 4; ++r) {
                    qa[(rb + r) * 68 + cc] = accQ[rf][c][r];
                    ka[(rb + r) * 68 + cc] = accK[rf][c][r];
                    va[(rb + r) * 68 + cc] = accV[rf][c][r];
                }
            }
        }
        __syncthreads();

        const float* qp = qa + ar * 68 + sub * 16;
        const float4 q0 = *(const float4*)(qp);
        const float4 q1 = *(const float4*)(qp + 4);
        const float4 q2 = *(const float4*)(qp + 8);
        const float4 q3 = *(const float4*)(qp + 12);
        float sc[4];
        #pragma unroll
        for (int ss = 0; ss < 4; ++ss) {
            const float* kp = ka + (ss * 16 + jj) * 68 + sub * 16;
            const float4 k0 = *(const float4*)(kp);
            const float4 k1 = *(const float4*)(kp + 4);
            const float4 k2 = *(const float4*)(kp + 8);
            const float4 k3 = *(const float4*)(kp + 12);
            float p = q0.x*k0.x + q0.y*k0.y + q0.z*k0.z + q0.w*k0.w
                    + q1.x*k1.x + q1.y*k1.y + q1.z*k1.z + q1.w*k1.w
                    + q2.x*k2.x + q2.y*k2.y + q2.z*k2.z + q2.w*k2.w
                    + q3.x*k3.x + q3.y*k3.y + q3.z*k3.z + q3.w*k3.w;
            p += __shfl_xor(p, 1);
            p += __shfl_xor(p, 2);
            sc[ss] = p;      // spike <=> (dot/8)/2 >= 1 <=> dot >= 16 (exact)
        }
        float o[16];
        #pragma unroll
        for (int d = 0; d < 16; ++d) o[d] = 0.f;
        #pragma unroll
        for (int ss = 0; ss < 4; ++ss) {
            if (sc[ss] >= 16.0f) {
                const float* vp = va + (ss * 16 + jj) * 68 + sub * 16;
                const float4 v0 = *(const float4*)(vp);
                const float4 v1 = *(const float4*)(vp + 4);
                const float4 v2 = *(const float4*)(vp + 8);
                const float4 v3 = *(const float4*)(vp + 12);
                o[0]+=v0.x; o[1]+=v0.y; o[2]+=v0.z;  o[3]+=v0.w;
                o[4]+=v1.x; o[5]+=v1.y; o[6]+=v1.z;  o[7]+=v1.w;
                o[8]+=v2.x; o[9]+=v2.y; o[10]+=v2.z; o[11]+=v2.w;
                o[12]+=v3.x;o[13]+=v3.y;o[14]+=v3.z; o[15]+=v3.w;
            }
        }
        f16x8 o0, o1;
        #pragma unroll
        for (int d = 0; d < 8; ++d) { o0[d] = (half_t)o[d]; o1[d] = (half_t)o[d + 8]; }
        const int grow = t_ * 1024 + (p0 >> 4) + hh;
        const int colb = h * 64 + sub * 16;
        const size_t cbase = ((size_t)(grow * 16 + (colb >> 5))) << 9;
        const int c0 = (colb >> 3) & 3;
        *(f16x8*)(acth + cbase + (size_t)((c0       * 16 + jj) << 3)) = o0;
        *(f16x8*)(acth + cbase + (size_t)(((c0 + 1) * 16 + jj) << 3)) = o1;
        __syncthreads();
    }
#undef K1_STAGE
}

// ---------------------------------------------------------------------------
// k2: out = act @ Wo^T + bo, fp16 MFMA, counted-vmcnt pipeline.
// ---------------------------------------------------------------------------
__global__ __launch_bounds__(256, 4)
void k2_gemm(const half_t* __restrict__ acth, const half_t* __restrict__ oh,
             const float* __restrict__ bo, float* __restrict__ out)
{
    __shared__ __align__(16) char smem[32768];

    const int tid  = threadIdx.x;
    const int lane = tid & 63;
    const int wv   = tid >> 6;
    const int wr   = wv >> 1, wc = wv & 1;
    const int l15  = lane & 15, l4 = lane >> 4;
    const int bn   = (blockIdx.x & 3) * 128;
    const int bm   = (blockIdx.x >> 2) * 128;

    const half_t* gb[4]; int lo_[4];
    #pragma unroll
    for (int ii = 0; ii < 4; ++ii) {
        const int i = wv * 4 + ii;
        if (i < 8) {
            const int grow = (bm >> 4) + i;
            gb[ii] = acth + ((size_t)grow << 13) + lane * 8;
            lo_[ii] = i * 1024;
        } else {
            const int fb = i - 8;
            const int grow = (bn >> 4) + fb;
            gb[ii] = oh + ((size_t)grow << 13) + lane * 8;
            lo_[ii] = 8192 + fb * 1024;
        }
    }

#define K2_STAGE(buf, kt) do {                                                  \
    _Pragma("unroll")                                                           \
    for (int ii = 0; ii < 4; ++ii)                                              \
        __builtin_amdgcn_global_load_lds(                                       \
            (const __attribute__((address_space(1))) void*)(gb[ii] + (size_t)(kt) * 512), \
            (__attribute__((address_space(3))) void*)(smem + (buf) * 16384 + lo_[ii]),    \
            16, 0, 0);                                                          \
    } while (0)

    f32x4 acc[4][4];
    #pragma unroll
    for (int rf = 0; rf < 4; ++rf)
        #pragma unroll
        for (int cf = 0; cf < 4; ++cf) acc[rf][cf] = f32x4{0.f, 0.f, 0.f, 0.f};

    K2_STAGE(0, 0);

    #pragma unroll
    for (int kt = 0; kt < NSTEP; ++kt) {
        const int cur = kt & 1;
        if (kt + 1 < NSTEP) {
            K2_STAGE(cur ^ 1, kt + 1);
            asm volatile("s_waitcnt vmcnt(4)" ::: "memory");
        } else {
            asm volatile("s_waitcnt vmcnt(0)" ::: "memory");
        }
        __builtin_amdgcn_sched_barrier(0);
        __builtin_amdgcn_s_barrier();

        const char* bp = smem + cur * 16384;
        f16x8 B[4];
        #pragma unroll
        for (int cf = 0; cf < 4; ++cf)
            B[cf] = *(const f16x8*)(bp + 8192 + (wc * 4 + cf) * 1024 + lane * 16);
        #pragma unroll
        for (int rf = 0; rf < 4; ++rf) {
            const f16x8 A = *(const f16x8*)(bp + (wr * 4 + rf) * 1024 + lane * 16);
            #pragma unroll
            for (int cf = 0; cf < 4; ++cf)
                acc[rf][cf] = MFMA_F16(A, B[cf], acc[rf][cf]);
        }
        asm volatile("s_waitcnt lgkmcnt(0)" ::: "memory");
        __builtin_amdgcn_s_barrier();
        __builtin_amdgcn_sched_barrier(0);
    }

    float bo4[4];
    #pragma unroll
    for (int cf = 0; cf < 4; ++cf) bo4[cf] = bo[bn + (wc * 4 + cf) * 16 + l15];

    #pragma unroll
    for (int rf = 0; rf < 4; ++rf) {
        const int row0 = bm + (wr * 4 + rf) * 16 + l4 * 4;
        #pragma unroll
        for (int cf = 0; cf < 4; ++cf) {
            const int col = bn + (wc * 4 + cf) * 16 + l15;
            #pragma unroll
            for (int r = 0; r < 4; ++r)
                out[(size_t)(row0 + r) * CCC + col] = acc[rf][cf][r] + bo4[cf];
        }
    }
#undef K2_STAGE
}

// ---------------------------------------------------------------------------
extern "C" void kernel_launch(void* const* d_in, const int* in_sizes, int n_in,
                              void* d_out, int out_size, void* d_ws, size_t ws_size,
                              hipStream_t stream)
{
    const float* x  = (const float*)d_in[0];
    const float* Wq = (const float*)d_in[1];
    const float* bq = (const float*)d_in[2];
    const float* Wk = (const float*)d_in[3];
    const float* bk = (const float*)d_in[4];
    const float* Wv = (const float*)d_in[5];
    const float* bv = (const float*)d_in[6];
    const float* Wo = (const float*)d_in[7];
    const float* bo = (const float*)d_in[8];

    half_t* ws   = (half_t*)d_ws;
    half_t* acth = ws + ACT_OFF;
    float*  out  = (float*)d_out;

    hipLaunchKernelGGL(k0_split, dim3(16896), dim3(256), 0, stream,
                       x, Wq, Wk, Wv, Wo, ws);
    hipLaunchKernelGGL(k1_mfma, dim3(4096), dim3(256), 0, stream,
                       ws, bq, bk, bv, acth);
    hipLaunchKernelGGL(k2_gemm, dim3(2048), dim3(256), 0, stream,
                       acth, ws + W_OFF + 5*WPL, bo, out);
}